// Round 1
// baseline (624.394 us; speedup 1.0000x reference)
//
#include <hip/hip_runtime.h>

// Problem constants (match reference)
constexpr int B  = 2;
constexpr int N  = 18432;          // divisible by 64 -> no tail lanes
constexpr int C  = 1024;
constexpr int GR = 40;
constexpr int NV = GR * GR * GR;   // 64000
constexpr int BNV = B * NV;        // 128000
constexpr int ZERO_VOX = 820;      // voxel of masked-to-origin points: 20 + 40*20

typedef float v4f __attribute__((ext_vector_type(4)));

// ---------------------------------------------------------------------------
// Kernel 1: per-point voxel id + validity; wave-aggregated hot atomics;
// valid points pushed onto a per-voxel linked list (head holds i+1, 0=empty).
// First pusher of a voxel also appends the voxel id to a worklist, so the
// gather pass only visits non-empty voxels (~15% of all voxels).
// ---------------------------------------------------------------------------
__global__ void points_kernel(const float* __restrict__ xyz,
                              int* __restrict__ cntAll,
                              int* __restrict__ head,
                              int* __restrict__ nxt,
                              int* __restrict__ bmax,
                              int* __restrict__ nWork,
                              int* __restrict__ worklist) {
    int i = blockIdx.x * blockDim.x + threadIdx.x;   // [0, B*N), no tail
    int b = i / N;                                   // wave-uniform (N % 64 == 0)
    int lane = threadIdx.x & 63;

    float x = xyz[3 * i + 0];
    float y = xyz[3 * i + 1];
    float z = xyz[3 * i + 2];

    bool valid = (x > -0.5f) && (x < 0.5f) &&
                 (y > -0.5f) && (y < 0.5f) &&
                 (z >  0.0f) && (z < 1.0f);

    // reference masks invalid xyz to 0 BEFORE voxelization
    float xm = valid ? x : 0.0f;
    float ym = valid ? y : 0.0f;
    float zm = valid ? z : 0.0f;

    int ix = min(max((int)floorf((xm + 0.5f) / 0.025f), 0), GR - 1);
    int iy = min(max((int)floorf((ym + 0.5f) / 0.025f), 0), GR - 1);
    int iz = min(max((int)floorf(zm / 0.025f), 0), GR - 1);
    int v = ix + GR * iy + GR * GR * iz;             // invalid -> ZERO_VOX

    // per-batch max voxel id: shfl-reduce, one atomic per wave
    int m = v;
    #pragma unroll
    for (int o = 32; o >= 1; o >>= 1)
        m = max(m, __shfl_xor(m, o, 64));
    if (lane == 0) atomicMax(&bmax[b], m);

    // denominator counts ALL points; invalid lanes all hit ZERO_VOX -> one
    // aggregated atomic per wave instead of ~27 serialized same-address adds
    unsigned long long vb = __ballot(valid);
    int nInv = 64 - __popcll(vb);
    if (lane == 0 && nInv > 0) atomicAdd(&cntAll[b * NV + ZERO_VOX], nInv);

    if (valid) {
        int g = b * NV + v;
        atomicAdd(&cntAll[g], 1);
        int old = atomicExch(&head[g], i + 1);       // push onto voxel list
        nxt[i] = old;
        if (old == 0) {                              // first VALID point in voxel
            int slot = atomicAdd(nWork, 1);
            worklist[slot] = g;                      // exactly-once per voxel
        }
    }
}

// ---------------------------------------------------------------------------
// Kernel 2: sparse gather. One block (256 threads, one float4 each) per
// NON-EMPTY voxel from the worklist. Walk the (short, avg ~1.09) point list,
// sum, multiply by 1/cnt, single nontemporal 16B store per thread.
// Empty voxels were already zeroed by the output memset (fast fill path).
// ---------------------------------------------------------------------------
__global__ void gather_sparse(const float* __restrict__ feats,
                              const int* __restrict__ head,
                              const int* __restrict__ nxt,
                              const int* __restrict__ cntAll,
                              const int* __restrict__ worklist,
                              const int* __restrict__ nWork,
                              float* __restrict__ out) {
    int e = blockIdx.x;
    if (e >= *nWork) return;                         // over-provisioned grid
    int g = worklist[e];
    int p = head[g];                                 // >= 1 by construction
    float inv = 1.0f / (float)cntAll[g];             // cnt >= 1 (has a valid pt)

    v4f acc = {0.0f, 0.0f, 0.0f, 0.0f};
    while (p) {
        int pn = nxt[p - 1];                         // prefetch next link
        const v4f* src = (const v4f*)(feats + (size_t)(p - 1) * C);
        acc += src[threadIdx.x];
        p = pn;
    }
    acc *= inv;
    v4f* dst = (v4f*)(out + (size_t)g * C);
    __builtin_nontemporal_store(acc, dst + threadIdx.x);
}

// ---------------------------------------------------------------------------
// Kernel 3: batch_offset = cumsum(max voxel id per batch + 1), as float
// ---------------------------------------------------------------------------
__global__ void offs_out_kernel(const int* __restrict__ bmax,
                                float* __restrict__ out_offs) {
    if (threadIdx.x == 0 && blockIdx.x == 0) {
        int m0 = bmax[0];
        int m1 = bmax[1];
        out_offs[0] = (float)(m0 + 1);
        out_offs[1] = (float)(m0 + 1 + m1 + 1);
    }
}

// ---------------------------------------------------------------------------
extern "C" void kernel_launch(void* const* d_in, const int* in_sizes, int n_in,
                              void* d_out, int out_size, void* d_ws, size_t ws_size,
                              hipStream_t stream) {
    const float* feats = (const float*)d_in[0];   // (B, N, C) fp32
    const float* xyz   = (const float*)d_in[1];   // (B, N, 3) fp32
    float* out = (float*)d_out;                   // pooled (B,NV,C) ++ batch_offset (B,)

    // workspace layout (int32): zeroed region first, one memset covers it
    int* w        = (int*)d_ws;
    int* cntAll   = w;                   // BNV   (zeroed)
    int* head     = cntAll + BNV;        // BNV   (zeroed; 0 = empty list)
    int* bmax     = head + BNV;          // B     (zeroed)
    int* nWork    = bmax + B;            // 1     (zeroed)
    int* worklist = nWork + 1;           // B*N   (no init needed)
    int* nxt      = worklist + B * N;    // B*N   (no init needed)

    hipMemsetAsync(cntAll, 0, (size_t)(2 * BNV + B + 1) * sizeof(int), stream);

    // Zero the pooled output via the dedicated fill path (~6.3 TB/s measured
    // on this chip) instead of a dense gather kernel writing mostly zeros.
    hipMemsetAsync(out, 0, (size_t)B * NV * C * sizeof(float), stream);

    // 64-thread blocks: 576 WGs spread across 256 CUs (vs 144 at 256 thr)
    points_kernel<<<(B * N) / 64, 64, 0, stream>>>(xyz, cntAll, head, nxt, bmax,
                                                   nWork, worklist);

    // worst case: every valid point lands in its own voxel -> B*N entries
    gather_sparse<<<B * N, 256, 0, stream>>>(feats, head, nxt, cntAll,
                                             worklist, nWork, out);

    offs_out_kernel<<<1, 64, 0, stream>>>(bmax, out + (size_t)B * NV * C);
}